// Round 2
// baseline (38.648 us; speedup 1.0000x reference)
//
#include <hip/hip_runtime.h>
#include <math.h>

#define S_ 4
#define NLAB 16
#define C1 32
#define C2 64
#define N_ 512
#define RC 6.0f
#define PI_OVER_RC 0.5235987755982988f  // pi/6

__global__ __launch_bounds__(64) void desc_kernel(
    const int* __restrict__ numbers,    // [B,N]
    const float* __restrict__ coords,   // [B,N,3]
    const float* __restrict__ nuww0, const float* __restrict__ sigmas0,
    const float* __restrict__ centres0, // [16,32]
    const float* __restrict__ nuww1, const float* __restrict__ sigmas1,
    const float* __restrict__ centres1, // [16,64]
    float* __restrict__ out)            // [B,N,4096]
{
    __shared__ float s_coords[N_ * 3];
    __shared__ int   s_num[N_];
    __shared__ float s_c0[NLAB * 33];   // padded stride 33 (bank-conflict)
    __shared__ float s_c1[NLAB * C2];
    __shared__ float s_ww0[NLAB], s_sg0[NLAB], s_ww1[NLAB], s_sg1[NLAB];
    __shared__ float nb_r4[N_ * 4];     // raij per compacted neighbor
    __shared__ float nb_s1[N_];
    __shared__ int   nb_lab[N_];
    __shared__ int   s_cnt;
    __shared__ float s_Lm[C2 * 4];

    const int tid = threadIdx.x;
    const int bi  = blockIdx.x;         // b*N + i
    const int b   = bi >> 9;
    const int i   = bi & (N_ - 1);

    // ---- stage inputs to LDS ----
    for (int idx = tid; idx < N_ * 3; idx += 64) s_coords[idx] = coords[b * N_ * 3 + idx];
    for (int idx = tid; idx < N_;     idx += 64) s_num[idx]    = numbers[b * N_ + idx];
    for (int idx = tid; idx < NLAB * C1; idx += 64) {
        int l = idx >> 5, c = idx & 31;
        s_c0[l * 33 + c] = centres0[idx];
    }
    for (int idx = tid; idx < NLAB * C2; idx += 64) s_c1[idx] = centres1[idx];
    if (tid < NLAB) {
        s_ww0[tid] = nuww0[tid]; s_sg0[tid] = sigmas0[tid];
        s_ww1[tid] = nuww1[tid]; s_sg1[tid] = sigmas1[tid];
    }
    if (tid == 0) s_cnt = 0;
    __syncthreads();

    const float xi = s_coords[i * 3 + 0];
    const float yi = s_coords[i * 3 + 1];
    const float zi = s_coords[i * 3 + 2];
    const int zlab = s_num[i] * S_;

    // ---- phase 1: neighbor scan + layer-0 scalar s1 ----
    for (int j = tid; j < N_; j += 64) {
        float dx = s_coords[j * 3 + 0] - xi;
        float dy = s_coords[j * 3 + 1] - yi;
        float dz = s_coords[j * 3 + 2] - zi;
        float d2 = dx * dx + dy * dy + dz * dz;
        float d  = sqrtf(d2);                       // match ref: test on rounded d
        bool m = (j != i) && (d <= RC);
        if (m) {
            float fc  = 0.5f * __cosf(d * PI_OVER_RC) + 0.5f;
            float fac = (d2 > 0.f) ? (fc / d) : 0.f;  // fc * (1/safe)
            int lab = zlab + s_num[j];
            float sg0 = s_sg0[lab];
            float s = 0.f;
            #pragma unroll
            for (int c = 0; c < C1; ++c) {
                float a = (fc - s_c0[lab * 33 + c]) * sg0;
                s += __expf(-(a * a));
            }
            int k = atomicAdd(&s_cnt, 1);
            nb_r4[k * 4 + 0] = fc;
            nb_r4[k * 4 + 1] = dx * fac;
            nb_r4[k * 4 + 2] = dy * fac;
            nb_r4[k * 4 + 3] = dz * fac;
            nb_s1[k]  = s_ww0[lab] * s;
            nb_lab[k] = lab;
        }
    }
    __syncthreads();
    const int nn = s_cnt;

    // ---- phase 2: thread tid owns channel c2 = tid; accumulate Lm row ----
    float a0 = 0.f, a1 = 0.f, a2 = 0.f, a3 = 0.f;
    for (int k = 0; k < nn; ++k) {
        int   lab = nb_lab[k];                       // broadcast
        float s1  = nb_s1[k];                        // broadcast
        float al  = (s1 - s_c1[lab * C2 + tid]) * s_sg1[lab];
        float p   = s_ww1[lab] * __expf(-(al * al));
        a0 += p * nb_r4[k * 4 + 0];
        a1 += p * nb_r4[k * 4 + 1];
        a2 += p * nb_r4[k * 4 + 2];
        a3 += p * nb_r4[k * 4 + 3];
    }
    s_Lm[tid * 4 + 0] = a0;
    s_Lm[tid * 4 + 1] = a1;
    s_Lm[tid * 4 + 2] = a2;
    s_Lm[tid * 4 + 3] = a3;
    __syncthreads();

    // ---- phase 3: R row tid = Lm[tid] . Lm[d]^T, Frobenius, write ----
    float rrow[C2];
    float ss = 0.f;
    #pragma unroll
    for (int d = 0; d < C2; ++d) {
        float r = a0 * s_Lm[d * 4 + 0] + a1 * s_Lm[d * 4 + 1]
                + a2 * s_Lm[d * 4 + 2] + a3 * s_Lm[d * 4 + 3];
        rrow[d] = r;
        ss += r * r;
    }
    // single-wave (64-lane) reduction for sum of squares
    #pragma unroll
    for (int off = 32; off >= 1; off >>= 1) ss += __shfl_xor(ss, off, 64);
    float inv = rsqrtf(ss);        // ss==0 -> inf -> 0*inf=NaN, same as ref 0/0

    float* po = out + (size_t)bi * (C2 * C2);
    // R is bitwise-symmetric: rrow[d] = R[tid][d] = R[d][tid]; write at
    // (d,tid) so consecutive lanes hit consecutive addresses (coalesced).
    #pragma unroll
    for (int d = 0; d < C2; ++d) {
        po[d * C2 + tid] = rrow[d] * inv;
    }
}

extern "C" void kernel_launch(void* const* d_in, const int* in_sizes, int n_in,
                              void* d_out, int out_size, void* d_ws, size_t ws_size,
                              hipStream_t stream) {
    // inputs: 0 boxs(f32,[B,9]) 1 numbers(i32,[B,N]) 2 coords(f32,[B,N,3])
    //         3 nuww0 4 sigmas0 5 centres0[16,32] 6 nuww1 7 sigmas1 8 centres1[16,64]
    const int*   numbers  = (const int*)  d_in[1];
    const float* coords   = (const float*)d_in[2];
    const float* nuww0    = (const float*)d_in[3];
    const float* sigmas0  = (const float*)d_in[4];
    const float* centres0 = (const float*)d_in[5];
    const float* nuww1    = (const float*)d_in[6];
    const float* sigmas1  = (const float*)d_in[7];
    const float* centres1 = (const float*)d_in[8];
    float* out = (float*)d_out;

    const int B = in_sizes[1] / N_;     // 4
    dim3 grid(B * N_), block(64);
    desc_kernel<<<grid, block, 0, stream>>>(numbers, coords, nuww0, sigmas0,
                                            centres0, nuww1, sigmas1, centres1, out);
}

// Round 3
// 18.989 us; speedup vs baseline: 2.0353x; 2.0353x over previous
//
#include <hip/hip_runtime.h>
#include <math.h>

#define S_ 4
#define NLAB 16
#define C1 32
#define C2 64
#define N_ 512
#define RC 6.0f
#define PI_OVER_RC 0.5235987755982988f  // pi/6
#define NBMAX 128                       // mean nn ~30 (density*sphere), max ~55; 128 is very safe

__global__ __launch_bounds__(256, 8) void desc_kernel(
    const int* __restrict__ numbers,    // [B,N]
    const float* __restrict__ coords,   // [B,N,3]
    const float* __restrict__ nuww0, const float* __restrict__ sigmas0,
    const float* __restrict__ centres0, // [16,32]
    const float* __restrict__ nuww1, const float* __restrict__ sigmas1,
    const float* __restrict__ centres1, // [16,64]
    float* __restrict__ out)            // [B,N,4096]
{
    __shared__ float s_c0[NLAB * C1];       // 2 KB
    __shared__ float s_c1[NLAB * C2];       // 4 KB
    __shared__ float s_ww0[NLAB], s_sg0[NLAB], s_ww1[NLAB], s_sg1[NLAB];
    __shared__ float nb_geo[NBMAX][4];      // dx,dy,dz,d   2 KB
    __shared__ float nb_r4[NBMAX][4];       // fc, ang*fc   2 KB
    __shared__ float nb_s1[NBMAX];          // 0.5 KB
    __shared__ int   nb_lab[NBMAX];         // 0.5 KB
    __shared__ int   s_cnt;
    __shared__ float s_Lm[C2][4];           // 1 KB
    __shared__ float s_part[4][C2][4];      // 4 KB
    __shared__ float s_ssp[4];

    const int tid  = threadIdx.x;           // 0..255
    const int w    = tid >> 6;               // wave 0..3
    const int lane = tid & 63;
    const int bi   = blockIdx.x;             // b*N + i
    const int b    = bi >> 9;
    const int i    = bi & (N_ - 1);
    const int base = b * N_;

    // ---- stage params to LDS (coords/numbers read direct: L1/L2 resident) ----
    for (int idx = tid; idx < NLAB * C1; idx += 256) s_c0[idx] = centres0[idx];
    for (int idx = tid; idx < NLAB * C2; idx += 256) s_c1[idx] = centres1[idx];
    if (tid < NLAB) {
        s_ww0[tid] = nuww0[tid]; s_sg0[tid] = sigmas0[tid];
        s_ww1[tid] = nuww1[tid]; s_sg1[tid] = sigmas1[tid];
    }
    if (tid == 0) s_cnt = 0;
    __syncthreads();

    const float xi = coords[(base + i) * 3 + 0];
    const float yi = coords[(base + i) * 3 + 1];
    const float zi = coords[(base + i) * 3 + 2];
    const int zlab = numbers[base + i] * S_;

    // ---- pass A: neighbor scan + compaction (cheap, no transcendentals) ----
    for (int j = tid; j < N_; j += 256) {    // 2 iters
        float dx = coords[(base + j) * 3 + 0] - xi;
        float dy = coords[(base + j) * 3 + 1] - yi;
        float dz = coords[(base + j) * 3 + 2] - zi;
        float d2 = dx * dx + dy * dy + dz * dz;
        float d  = sqrtf(d2);                // match ref: test on rounded d
        if (j != i && d <= RC) {
            int k = atomicAdd(&s_cnt, 1);
            if (k < NBMAX) {
                nb_geo[k][0] = dx; nb_geo[k][1] = dy;
                nb_geo[k][2] = dz; nb_geo[k][3] = d;
                nb_lab[k] = zlab + numbers[base + j];
            }
        }
    }
    __syncthreads();
    const int nn = min(s_cnt, NBMAX);

    // ---- pass B: per-neighbor fc + layer-0 scalar s1, 8 lanes per neighbor ----
    {
        const int cp = tid & 7;              // channel-part 0..7 (4 channels each)
        for (int k = tid >> 3; k < nn; k += 32) {
            float d   = nb_geo[k][3];
            int   lab = nb_lab[k];
            float fc  = 0.5f * __cosf(d * PI_OVER_RC) + 0.5f;
            float sg0 = s_sg0[lab];
            float p0 = 0.f, p1 = 0.f;
            #pragma unroll
            for (int q = 0; q < 4; q += 2) {
                float a0 = (fc - s_c0[lab * C1 + cp * 4 + q])     * sg0;
                float a1 = (fc - s_c0[lab * C1 + cp * 4 + q + 1]) * sg0;
                p0 += __expf(-(a0 * a0));
                p1 += __expf(-(a1 * a1));
            }
            float s = p0 + p1;
            s += __shfl_xor(s, 1, 64);       // groups of 8 are wave-aligned
            s += __shfl_xor(s, 2, 64);
            s += __shfl_xor(s, 4, 64);
            float fac = (d > 0.f) ? (fc / d) : 0.f;
            if (cp < 4) {
                float v = (cp == 0) ? fc : nb_geo[k][cp - 1] * fac;
                nb_r4[k][cp] = v;
            }
            if (cp == 0) nb_s1[k] = s_ww0[lab] * s;
        }
    }
    __syncthreads();

    // ---- phase 2: lane = channel, wave w takes neighbors k = w, w+4, ... ----
    {
        float a0 = 0.f, a1 = 0.f, a2 = 0.f, a3 = 0.f;
        for (int k = w; k < nn; k += 4) {
            int   lab = nb_lab[k];           // broadcast
            float s1  = nb_s1[k];            // broadcast
            float al  = (s1 - s_c1[lab * C2 + lane]) * s_sg1[lab];
            float p   = s_ww1[lab] * __expf(-(al * al));
            a0 += p * nb_r4[k][0];
            a1 += p * nb_r4[k][1];
            a2 += p * nb_r4[k][2];
            a3 += p * nb_r4[k][3];
        }
        s_part[w][lane][0] = a0; s_part[w][lane][1] = a1;
        s_part[w][lane][2] = a2; s_part[w][lane][3] = a3;
    }
    __syncthreads();
    if (tid < C2) {
        #pragma unroll
        for (int f = 0; f < 4; ++f) {
            s_Lm[tid][f] = (s_part[0][tid][f] + s_part[1][tid][f])
                         + (s_part[2][tid][f] + s_part[3][tid][f]);
        }
    }
    __syncthreads();

    // ---- phase 3: R = Lm Lm^T, Frobenius normalize, write 16 elems/thread ----
    float ss = 0.f;
    #pragma unroll
    for (int q = 0; q < 16; ++q) {
        int e = q * 256 + tid;
        int dd = e >> 6;                     // uniform per (q, wave)
        int c  = e & 63;                     // = lane
        float r = s_Lm[c][0] * s_Lm[dd][0] + s_Lm[c][1] * s_Lm[dd][1]
                + s_Lm[c][2] * s_Lm[dd][2] + s_Lm[c][3] * s_Lm[dd][3];
        ss += r * r;
    }
    #pragma unroll
    for (int off = 32; off >= 1; off >>= 1) ss += __shfl_xor(ss, off, 64);
    if (lane == 0) s_ssp[w] = ss;
    __syncthreads();
    float tot = (s_ssp[0] + s_ssp[1]) + (s_ssp[2] + s_ssp[3]);
    float inv = rsqrtf(tot);                 // ss==0 -> inf -> NaN, same as ref 0/0

    float* po = out + (size_t)bi * (C2 * C2);
    #pragma unroll
    for (int q = 0; q < 16; ++q) {           // recompute r: saves 16 VGPRs
        int e = q * 256 + tid;
        int dd = e >> 6;
        int c  = e & 63;
        float r = s_Lm[c][0] * s_Lm[dd][0] + s_Lm[c][1] * s_Lm[dd][1]
                + s_Lm[c][2] * s_Lm[dd][2] + s_Lm[c][3] * s_Lm[dd][3];
        po[e] = r * inv;
    }
}

extern "C" void kernel_launch(void* const* d_in, const int* in_sizes, int n_in,
                              void* d_out, int out_size, void* d_ws, size_t ws_size,
                              hipStream_t stream) {
    // inputs: 0 boxs(f32,[B,9]) 1 numbers(i32,[B,N]) 2 coords(f32,[B,N,3])
    //         3 nuww0 4 sigmas0 5 centres0[16,32] 6 nuww1 7 sigmas1 8 centres1[16,64]
    const int*   numbers  = (const int*)  d_in[1];
    const float* coords   = (const float*)d_in[2];
    const float* nuww0    = (const float*)d_in[3];
    const float* sigmas0  = (const float*)d_in[4];
    const float* centres0 = (const float*)d_in[5];
    const float* nuww1    = (const float*)d_in[6];
    const float* sigmas1  = (const float*)d_in[7];
    const float* centres1 = (const float*)d_in[8];
    float* out = (float*)d_out;

    const int B = in_sizes[1] / N_;          // 4
    dim3 grid(B * N_), block(256);
    desc_kernel<<<grid, block, 0, stream>>>(numbers, coords, nuww0, sigmas0,
                                            centres0, nuww1, sigmas1, centres1, out);
}

// Round 4
// 18.160 us; speedup vs baseline: 2.1282x; 1.0456x over previous
//
#include <hip/hip_runtime.h>
#include <math.h>

#define S_ 4
#define NLAB 16
#define C1 32
#define C2 64
#define N_ 512
#define RC 6.0f
#define PI_OVER_RC 0.5235987755982988f  // pi/6
#define NBMAX 128                       // mean nn ~30, max ~55; 128 is very safe

__global__ __launch_bounds__(256, 4) void desc_kernel(
    const int* __restrict__ numbers,    // [B,N]
    const float* __restrict__ coords,   // [B,N,3]
    const float* __restrict__ nuww0, const float* __restrict__ sigmas0,
    const float* __restrict__ centres0, // [16,32]
    const float* __restrict__ nuww1, const float* __restrict__ sigmas1,
    const float* __restrict__ centres1, // [16,64]
    float* __restrict__ out)            // [B,N,4096]
{
    __shared__ float s_c0[NLAB * C1];       // 2 KB
    __shared__ float s_c1[NLAB * C2];       // 4 KB
    __shared__ float s_ww0[NLAB], s_sg0[NLAB], s_ww1[NLAB], s_sg1[NLAB];
    __shared__ float nb_geo[NBMAX][4];      // dx,dy,dz,d   2 KB
    __shared__ float nb_r4[NBMAX][4];       // fc, ang*fc   2 KB
    __shared__ float nb_s1[NBMAX];          // 0.5 KB
    __shared__ int   nb_lab[NBMAX];         // 0.5 KB
    __shared__ int   s_cnt;
    __shared__ float s_Lm[C2][4];           // 1 KB
    __shared__ float s_part[4][C2][4];      // 4 KB
    __shared__ float s_ssp[4];

    const int tid  = threadIdx.x;           // 0..255
    const int w    = tid >> 6;              // wave 0..3
    const int lane = tid & 63;
    const int bi   = blockIdx.x;            // b*N + i
    const int b    = bi >> 9;
    const int i    = bi & (N_ - 1);
    const int base = b * N_;

    // ---- stage params to LDS (coords/numbers read direct: L1/L2 resident) ----
    for (int idx = tid; idx < NLAB * C1; idx += 256) s_c0[idx] = centres0[idx];
    for (int idx = tid; idx < NLAB * C2; idx += 256) s_c1[idx] = centres1[idx];
    if (tid < NLAB) {
        s_ww0[tid] = nuww0[tid]; s_sg0[tid] = sigmas0[tid];
        s_ww1[tid] = nuww1[tid]; s_sg1[tid] = sigmas1[tid];
    }
    if (tid == 0) s_cnt = 0;
    __syncthreads();

    const float xi = coords[(base + i) * 3 + 0];
    const float yi = coords[(base + i) * 3 + 1];
    const float zi = coords[(base + i) * 3 + 2];
    const int zlab = numbers[base + i] * S_;

    // ---- pass A: neighbor scan + compaction (cheap, no transcendentals) ----
    for (int j = tid; j < N_; j += 256) {    // 2 iters
        float dx = coords[(base + j) * 3 + 0] - xi;
        float dy = coords[(base + j) * 3 + 1] - yi;
        float dz = coords[(base + j) * 3 + 2] - zi;
        float d2 = dx * dx + dy * dy + dz * dz;
        float d  = sqrtf(d2);                // match ref: test on rounded d
        if (j != i && d <= RC) {
            int k = atomicAdd(&s_cnt, 1);
            if (k < NBMAX) {
                nb_geo[k][0] = dx; nb_geo[k][1] = dy;
                nb_geo[k][2] = dz; nb_geo[k][3] = d;
                nb_lab[k] = zlab + numbers[base + j];
            }
        }
    }
    __syncthreads();
    const int nn = min(s_cnt, NBMAX);

    // ---- pass B: per-neighbor fc + layer-0 scalar s1, 8 lanes per neighbor ----
    {
        const int cp = tid & 7;              // channel-part 0..7 (4 channels each)
        for (int k = tid >> 3; k < nn; k += 32) {
            float d   = nb_geo[k][3];
            int   lab = nb_lab[k];
            float fc  = 0.5f * __cosf(d * PI_OVER_RC) + 0.5f;
            float sg0 = s_sg0[lab];
            float p0 = 0.f, p1 = 0.f;
            #pragma unroll
            for (int q = 0; q < 4; q += 2) {
                float a0 = (fc - s_c0[lab * C1 + cp * 4 + q])     * sg0;
                float a1 = (fc - s_c0[lab * C1 + cp * 4 + q + 1]) * sg0;
                p0 += __expf(-(a0 * a0));
                p1 += __expf(-(a1 * a1));
            }
            float s = p0 + p1;
            s += __shfl_xor(s, 1, 64);       // groups of 8 are wave-aligned
            s += __shfl_xor(s, 2, 64);
            s += __shfl_xor(s, 4, 64);
            float fac = (d > 0.f) ? (fc / d) : 0.f;
            if (cp < 4) {
                float v = (cp == 0) ? fc : nb_geo[k][cp - 1] * fac;
                nb_r4[k][cp] = v;
            }
            if (cp == 0) nb_s1[k] = s_ww0[lab] * s;
        }
    }
    __syncthreads();

    // ---- phase 2: lane = channel, wave w takes neighbors k = w, w+4, ... ----
    {
        float a0 = 0.f, a1 = 0.f, a2 = 0.f, a3 = 0.f;
        for (int k = w; k < nn; k += 4) {
            int   lab = nb_lab[k];           // broadcast
            float s1  = nb_s1[k];            // broadcast
            float al  = (s1 - s_c1[lab * C2 + lane]) * s_sg1[lab];
            float p   = s_ww1[lab] * __expf(-(al * al));
            a0 += p * nb_r4[k][0];
            a1 += p * nb_r4[k][1];
            a2 += p * nb_r4[k][2];
            a3 += p * nb_r4[k][3];
        }
        s_part[w][lane][0] = a0; s_part[w][lane][1] = a1;
        s_part[w][lane][2] = a2; s_part[w][lane][3] = a3;
    }
    __syncthreads();
    if (tid < C2) {
        #pragma unroll
        for (int f = 0; f < 4; ++f) {
            s_Lm[tid][f] = (s_part[0][tid][f] + s_part[1][tid][f])
                         + (s_part[2][tid][f] + s_part[3][tid][f]);
        }
    }
    __syncthreads();

    // ---- phase 3: R = Lm Lm^T, Frobenius normalize, float4 writes ----
    // element e = q*1024 + tid*4 + j  (q=0..3, j=0..3) -> row dd = e>>6, col c = e&63
    float rr[16];
    float ss = 0.f;
    #pragma unroll
    for (int q = 0; q < 4; ++q) {
        int dd = q * 16 + (tid >> 4);        // uniform per 16 threads
        float L0 = s_Lm[dd][0], L1 = s_Lm[dd][1], L2 = s_Lm[dd][2], L3 = s_Lm[dd][3];
        #pragma unroll
        for (int j = 0; j < 4; ++j) {
            int c = ((tid << 2) & 63) + j;
            float r = s_Lm[c][0] * L0 + s_Lm[c][1] * L1
                    + s_Lm[c][2] * L2 + s_Lm[c][3] * L3;
            rr[q * 4 + j] = r;
            ss += r * r;
        }
    }
    #pragma unroll
    for (int off = 32; off >= 1; off >>= 1) ss += __shfl_xor(ss, off, 64);
    if (lane == 0) s_ssp[w] = ss;
    __syncthreads();
    float tot = (s_ssp[0] + s_ssp[1]) + (s_ssp[2] + s_ssp[3]);
    float inv = rsqrtf(tot);                 // ss==0 -> inf -> NaN, same as ref 0/0

    float* po = out + (size_t)bi * (C2 * C2);
    #pragma unroll
    for (int q = 0; q < 4; ++q) {
        float4 v;
        v.x = rr[q * 4 + 0] * inv;
        v.y = rr[q * 4 + 1] * inv;
        v.z = rr[q * 4 + 2] * inv;
        v.w = rr[q * 4 + 3] * inv;
        *reinterpret_cast<float4*>(po + q * 1024 + tid * 4) = v;
    }
}

extern "C" void kernel_launch(void* const* d_in, const int* in_sizes, int n_in,
                              void* d_out, int out_size, void* d_ws, size_t ws_size,
                              hipStream_t stream) {
    // inputs: 0 boxs(f32,[B,9]) 1 numbers(i32,[B,N]) 2 coords(f32,[B,N,3])
    //         3 nuww0 4 sigmas0 5 centres0[16,32] 6 nuww1 7 sigmas1 8 centres1[16,64]
    const int*   numbers  = (const int*)  d_in[1];
    const float* coords   = (const float*)d_in[2];
    const float* nuww0    = (const float*)d_in[3];
    const float* sigmas0  = (const float*)d_in[4];
    const float* centres0 = (const float*)d_in[5];
    const float* nuww1    = (const float*)d_in[6];
    const float* sigmas1  = (const float*)d_in[7];
    const float* centres1 = (const float*)d_in[8];
    float* out = (float*)d_out;

    const int B = in_sizes[1] / N_;          // 4
    dim3 grid(B * N_), block(256);
    desc_kernel<<<grid, block, 0, stream>>>(numbers, coords, nuww0, sigmas0,
                                            centres0, nuww1, sigmas1, centres1, out);
}